// Round 1
// baseline (662.711 us; speedup 1.0000x reference)
//
#include <hip/hip_runtime.h>

// Problem constants (fixed by reference file)
#define NROWS   16384
#define HDIM    2048
#define TOPK    4
#define NEXP    64
#define NSLOT   (NROWS * TOPK)        // 65536 expanded slots
#define SLOTS_PER_BLOCK 256
#define NBLK    (NSLOT / SLOTS_PER_BLOCK)  // 256 histogram blocks

// ---------------------------------------------------------------------------
// K1: per-block histogram of expert ids (256 slots/block, LDS atomics)
// ---------------------------------------------------------------------------
__global__ void hist_kernel(const int* __restrict__ eidx, int* __restrict__ hist) {
    __shared__ int h[NEXP];
    int t = threadIdx.x;
    if (t < NEXP) h[t] = 0;
    __syncthreads();
    int slot = blockIdx.x * SLOTS_PER_BLOCK + t;
    int e = eidx[slot];
    atomicAdd(&h[e], 1);
    __syncthreads();
    if (t < NEXP) hist[blockIdx.x * NEXP + t] = h[t];
}

// ---------------------------------------------------------------------------
// K2: single wave (64 threads, one per expert).
//   totals -> expert_tokens_count output (as float)
//   exclusive scan across experts (shfl) -> expert offsets
//   running prefix over blocks -> base[block][expert]
// ---------------------------------------------------------------------------
__global__ void scan_kernel(const int* __restrict__ hist, int* __restrict__ base,
                            float* __restrict__ out_counts) {
    int e = threadIdx.x;   // 0..63
    int total = 0;
    #pragma unroll 8
    for (int b = 0; b < NBLK; ++b) total += hist[b * NEXP + e];
    out_counts[e] = (float)total;

    // inclusive scan across the 64-lane wave
    int incl = total;
    #pragma unroll
    for (int d = 1; d < 64; d <<= 1) {
        int y = __shfl_up(incl, d, 64);
        if (e >= d) incl += y;
    }
    int running = incl - total;   // exclusive offset for expert e
    for (int b = 0; b < NBLK; ++b) {
        base[b * NEXP + e] = running;
        running += hist[b * NEXP + e];
    }
}

// ---------------------------------------------------------------------------
// K3: stable in-block rank -> destination slot.
//   Writes expanded_row_idx (float), expanded_scale (scattered), dest map (ws).
//   Rank loop reads LDS at a wave-uniform address each iter => broadcast,
//   conflict-free.
// ---------------------------------------------------------------------------
__global__ void rank_kernel(const int* __restrict__ eidx, const int* __restrict__ base,
                            const float* __restrict__ scale,
                            int* __restrict__ dest_ws, float* __restrict__ out_idx,
                            float* __restrict__ out_scale) {
    __shared__ int se[SLOTS_PER_BLOCK];
    int t = threadIdx.x;
    int slot = blockIdx.x * SLOTS_PER_BLOCK + t;
    int e = eidx[slot];
    se[t] = e;
    __syncthreads();
    int rank = 0;
    #pragma unroll 8
    for (int i = 0; i < SLOTS_PER_BLOCK; ++i) {
        int v = se[i];
        rank += (i < t && v == e) ? 1 : 0;
    }
    int dest = base[blockIdx.x * NEXP + e] + rank;
    dest_ws[slot] = dest;
    out_idx[slot] = (float)dest;
    out_scale[dest] = scale[slot >> 2];   // slot/TOPK
}

// ---------------------------------------------------------------------------
// K4: the gather. One block per expanded row; 256 threads x 2 float4 = 2048 f32.
// Writes are fully coalesced 16B/lane; reads hit L3 (x = 128 MiB < 256 MiB L3).
// ---------------------------------------------------------------------------
__global__ void __launch_bounds__(256) copy_kernel(const float4* __restrict__ x,
                                                   const int* __restrict__ dest_ws,
                                                   float4* __restrict__ out) {
    int slot = blockIdx.x;
    int dest = dest_ws[slot];        // wave-uniform address -> scalar-ish load
    int src  = slot >> 2;            // slot / TOPK
    const float4* xs = x   + (size_t)src  * (HDIM / 4);
    float4*       od = out + (size_t)dest * (HDIM / 4);
    int t = threadIdx.x;
    od[t]       = xs[t];
    od[t + 256] = xs[t + 256];
}

extern "C" void kernel_launch(void* const* d_in, const int* in_sizes, int n_in,
                              void* d_out, int out_size, void* d_ws, size_t ws_size,
                              hipStream_t stream) {
    const float* x     = (const float*)d_in[0];
    const int*   eidx  = (const int*)d_in[1];
    const float* scale = (const float*)d_in[2];
    // d_in[3] = expert_num (64), compile-time constant here.

    float* out        = (float*)d_out;
    float* out_x      = out;                                   // [65536, 2048]
    float* out_idx    = out + (size_t)NSLOT * HDIM;            // [65536]
    float* out_counts = out_idx + NSLOT;                       // [64]
    float* out_scale  = out_counts + NEXP;                     // [65536]

    int* hist = (int*)d_ws;                 // [NBLK * NEXP]   64 KiB
    int* base = hist + NBLK * NEXP;         // [NBLK * NEXP]   64 KiB
    int* dest = base + NBLK * NEXP;         // [NSLOT]        256 KiB

    hist_kernel<<<NBLK, SLOTS_PER_BLOCK, 0, stream>>>(eidx, hist);
    scan_kernel<<<1, 64, 0, stream>>>(hist, base, out_counts);
    rank_kernel<<<NBLK, SLOTS_PER_BLOCK, 0, stream>>>(eidx, base, scale,
                                                      dest, out_idx, out_scale);
    copy_kernel<<<NSLOT, 256, 0, stream>>>((const float4*)x, dest, (float4*)out_x);
}